// Round 5
// baseline (868.908 us; speedup 1.0000x reference)
//
#include <hip/hip_runtime.h>
#include <math.h>

#define B_ 128
#define D_ 128
#define P_ 4
#define M_ 100000
#define K_ 10
#define SCALE_ 10.0f
#define MB_ 782                     // ceil(100000/128)
#define POSB_ 128
#define MMDB_ 128
#define NEGB_ (MB_ * P_)            // 3128
#define TOTB_ (POSB_ + MMDB_ + NEGB_)   // 3384
#define D2_CUT 120.0f               // d2 >= 120 -> expf(-10*sqrtf(d2)) == 0.0f exactly

typedef short bf16x8 __attribute__((ext_vector_type(8)));
typedef float floatx4 __attribute__((ext_vector_type(4)));

// pack two fp32 -> two bf16 (truncate) in one v_perm_b32
__device__ inline unsigned pack_bf16_trunc(unsigned f0, unsigned f1) {
    return __builtin_amdgcn_perm(f1, f0, 0x07060302u);
}

// ---------- cross-lane helpers ----------
template <int CTRL>
__device__ inline float dpp_add(float v) {
    int x = __builtin_amdgcn_update_dpp(0, __builtin_bit_cast(int, v), CTRL, 0xF, 0xF, true);
    return v + __builtin_bit_cast(float, x);
}
__device__ inline float row16Sum(float v) {          // sum over 16-lane rows
    v = dpp_add<0xB1>(v);     // xor1
    v = dpp_add<0x4E>(v);     // xor2
    v = dpp_add<0x141>(v);    // row_half_mirror (xor4 within 8)
    v = dpp_add<0x140>(v);    // row_mirror (xor8 within 16)
    return v;
}
__device__ inline float waveSum64(float v) {
    v = row16Sum(v);
    v += __shfl_xor(v, 16, 64);
    v += __shfl_xor(v, 32, 64);
    return v;
}
__device__ inline float waveReduceSumOld(float v) {  // mmd path: keep r3/r4 order
    #pragma unroll
    for (int off = 32; off > 0; off >>= 1) v += __shfl_xor(v, off, 64);
    return v;
}

// ---------- the one kernel ----------
// bid < 128:            pos blocks (4 waves, one (p,b) pair each)
// 128 <= bid < 256:     mmd row blocks (self-normalizing)
// bid >= 256:           neg MFMA blocks (128 m-rows each)
// every block: fence + counter; last block computes final scalars.
__global__ __launch_bounds__(256, 3) void k_main(const float* __restrict__ local,
                                                 const float* __restrict__ centers,
                                                 const float* __restrict__ img,
                                                 const float* __restrict__ txt,
                                                 const int* __restrict__ ci,
                                                 const int* __restrict__ posi,
                                                 const int* __restrict__ mvid,
                                                 float* __restrict__ s_neg,
                                                 float* __restrict__ s_pos,
                                                 double* __restrict__ mmd_part,
                                                 int* __restrict__ counter,
                                                 float* __restrict__ out) {
    union Smem {
        struct {
            bf16x8 A_lds[2048];     // 32 KB fragment-order A
            float sred[512];
            float f2l[128];         // 16B-aligned (offset 34816)
            unsigned char msk[128];
        } n;
        struct {
            float ri[128], rt[128];
            float rsqi[128], rsqt[128];
            float a2ii[128], a2tt[128];
            float sh2[2];
        } m;
    };
    __shared__ Smem sm;
    __shared__ int last_flag;
    __shared__ float lred[4];

    const int bid = blockIdx.x;
    const int t = threadIdx.x;
    const int w = t >> 6;
    const int l = t & 63;

    if (bid < POSB_) {
        // ================= pos: one wave per (p,b) =================
        const int pair = bid * 4 + w;          // 0..511
        const int p = pair >> 7, b = pair & 127;
        const float* f = local + (size_t)pair * D_;
        float f0 = f[l], f1 = f[l + 64];
        float f2v = waveSum64(f0 * f0 + f1 * f1);
        const float* cb = centers + (size_t)p * M_ * D_;
        float s = 0.f;
        #pragma unroll
        for (int k = 0; k < K_; k++) {
            int idx = ci[b * K_ + k];
            const float* c = cb + (size_t)idx * D_;
            float c0 = c[l], c1 = c[l + 64];
            float p2 = waveSum64(c0 * c0 + c1 * c1);
            float fp = waveSum64(f0 * c0 + f1 * c1);
            float d2 = fmaxf(f2v + p2 - 2.f * fp, 0.f);
            if (d2 < D2_CUT) s += expf(-SCALE_ * sqrtf(d2));   // wave-uniform branch
        }
        if (l == 0) s_pos[pair] = s;
        if (p == 0 && l < K_) {
            int ix = ci[b * K_ + l];
            out[3 + b * K_ + l] = (float)mvid[ix];
        }
    } else if (bid < POSB_ + MMDB_) {
        // ================= mmd (row i), self-normalizing =================
        const int i = bid - POSB_;
        if (t < 128) {
            float si = 0.f, st = 0.f;
            const float* pi = img + (size_t)t * D_;
            const float* pt = txt + (size_t)t * D_;
            #pragma unroll 4
            for (int d = 0; d < D_; d++) {
                float a = pi[d], b = pt[d];
                si = fmaf(a, a, si);
                st = fmaf(b, b, st);
            }
            float ri_ = 1.f / sqrtf(si), rt_ = 1.f / sqrtf(st);
            sm.m.rsqi[t] = ri_;
            sm.m.rsqt[t] = rt_;
            sm.m.a2ii[t] = si * ri_ * ri_;
            sm.m.a2tt[t] = st * rt_ * rt_;
        }
        __syncthreads();
        if (t < 128) {
            sm.m.ri[t] = img[(size_t)i * D_ + t] * sm.m.rsqi[i];
            sm.m.rt[t] = txt[(size_t)i * D_ + t] * sm.m.rsqt[i];
        }
        __syncthreads();
        float kxx = 0.f, kyy = 0.f, kxy = 0.f;
        if (t < 128) {
            float rq = sm.m.rsqi[t], rqt = sm.m.rsqt[t];
            const float* pi = img + (size_t)t * D_;
            const float* pt = txt + (size_t)t * D_;
            float dxx = 0.f, dyy = 0.f, dxy = 0.f;
            #pragma unroll 4
            for (int d = 0; d < D_; d++) {
                float av = pi[d] * rq;
                float bv = pt[d] * rqt;
                dxx = fmaf(sm.m.ri[d], av, dxx);
                dyy = fmaf(sm.m.rt[d], bv, dyy);
                dxy = fmaf(sm.m.ri[d], bv, dxy);
            }
            float a2ii_i = sm.m.a2ii[i], a2tt_i = sm.m.a2tt[i];
            kxx = (i == t) ? 0.f : expf(-fmaxf(a2ii_i + sm.m.a2ii[t] - 2.f * dxx, 0.f) * 0.5f);
            kyy = (i == t) ? 0.f : expf(-fmaxf(a2tt_i + sm.m.a2tt[t] - 2.f * dyy, 0.f) * 0.5f);
            kxy = expf(-fmaxf(a2ii_i + sm.m.a2tt[t] - 2.f * dxy, 0.f) * 0.5f);
        }
        float sxx = waveReduceSumOld(kxx);
        float syy = waveReduceSumOld(kyy);
        float sxy = waveReduceSumOld(kxy);
        __syncthreads();
        if (t == 0)  sm.m.sh2[0] = sxx;
        if (t == 64) sm.m.sh2[1] = sxx;
        __syncthreads();
        float txx = sm.m.sh2[0] + sm.m.sh2[1];
        __syncthreads();
        if (t == 0)  sm.m.sh2[0] = syy;
        if (t == 64) sm.m.sh2[1] = syy;
        __syncthreads();
        float tyy = sm.m.sh2[0] + sm.m.sh2[1];
        __syncthreads();
        if (t == 0)  sm.m.sh2[0] = sxy;
        if (t == 64) sm.m.sh2[1] = sxy;
        __syncthreads();
        float txy = sm.m.sh2[0] + sm.m.sh2[1];
        if (t == 0) {
            mmd_part[i] = (double)txx;
            mmd_part[128 + i] = (double)tyy;
            mmd_part[256 + i] = (double)txy;
        }
    } else {
        // ================= neg: bf16 MFMA tile =================
        const int idx = bid - (POSB_ + MMDB_);
        const int p = idx / MB_;
        const int mb = idx - p * MB_;
        const int m0 = mb * 128;
        const int n16 = l & 15;
        const int q = l >> 4;

        if (t < 128) { sm.n.msk[t] = 1; sm.n.f2l[t] = 0.f; }
        __syncthreads();

        // ---- stage A = local[p] as bf16 fragments + f2 via LDS atomics ----
        const float* lp = local + (size_t)p * B_ * D_;
        #pragma unroll
        for (int s8 = 0; s8 < 8; s8++) {
            int f = t + 256 * s8;
            int fl = f & 63, bt = (f >> 6) & 7, kc = f >> 9;
            int row = bt * 16 + (fl & 15);
            int col = kc * 32 + ((fl >> 4) & 3) * 8;
            union { uint4 u; floatx4 fv; } a, b;
            a.u = *(const uint4*)(lp + row * D_ + col);
            b.u = *(const uint4*)(lp + row * D_ + col + 4);
            float pr = a.fv[0]*a.fv[0] + a.fv[1]*a.fv[1] + a.fv[2]*a.fv[2] + a.fv[3]*a.fv[3]
                     + b.fv[0]*b.fv[0] + b.fv[1]*b.fv[1] + b.fv[2]*b.fv[2] + b.fv[3]*b.fv[3];
            atomicAdd(&sm.n.f2l[row], pr);
            union { bf16x8 v; unsigned u[4]; } fr;
            fr.u[0] = pack_bf16_trunc(a.u.x, a.u.y);
            fr.u[1] = pack_bf16_trunc(a.u.z, a.u.w);
            fr.u[2] = pack_bf16_trunc(b.u.x, b.u.y);
            fr.u[3] = pack_bf16_trunc(b.u.z, b.u.w);
            sm.n.A_lds[f] = fr.v;
        }
        __syncthreads();

        // ---- issue ALL B loads (16 x 16B in flight per thread) ----
        int gm[2];
        gm[0] = m0 + (w * 2 + 0) * 16 + n16;
        gm[1] = m0 + (w * 2 + 1) * 16 + n16;
        const float* cb = centers + (size_t)p * M_ * D_;
        uint4 rb[2][4][2];
        if (m0 + 128 <= M_) {
            #pragma unroll
            for (int wm = 0; wm < 2; wm++) {
                const uint4* src = (const uint4*)(cb + (size_t)gm[wm] * D_ + q * 8);
                #pragma unroll
                for (int kc = 0; kc < 4; kc++) {
                    rb[wm][kc][0] = src[kc * 8];
                    rb[wm][kc][1] = src[kc * 8 + 1];
                }
            }
        } else {
            const uint4 z = make_uint4(0u, 0u, 0u, 0u);
            #pragma unroll
            for (int wm = 0; wm < 2; wm++) {
                const uint4* src = (const uint4*)(cb + (size_t)gm[wm] * D_ + q * 8);
                #pragma unroll
                for (int kc = 0; kc < 4; kc++) {
                    if (gm[wm] < M_) {
                        rb[wm][kc][0] = src[kc * 8];
                        rb[wm][kc][1] = src[kc * 8 + 1];
                    } else {
                        rb[wm][kc][0] = z;
                        rb[wm][kc][1] = z;
                    }
                }
            }
        }

        // ---- scatter mask zeros (overlaps load latency) ----
        #pragma unroll
        for (int i = 0; i < 5; i++) {             // 5*256 = B_*K_
            int ix = ci[t + 256 * i];
            unsigned r = (unsigned)(ix - m0);
            if (r < 128u) sm.n.msk[r] = 0;
        }
        if (t < B_) {
            unsigned r = (unsigned)(posi[t] - m0);
            if (r < 128u) sm.n.msk[r] = 0;
        }
        __syncthreads();

        // ---- c2 + convert to bf16 fragments ----
        float c2a[2];
        bf16x8 bfr[2][4];
        #pragma unroll
        for (int wm = 0; wm < 2; wm++) {
            float c = 0.f;
            #pragma unroll
            for (int kc = 0; kc < 4; kc++) {
                union { uint4 u; floatx4 fv; } a, b;
                a.u = rb[wm][kc][0];
                b.u = rb[wm][kc][1];
                c += a.fv[0]*a.fv[0] + a.fv[1]*a.fv[1] + a.fv[2]*a.fv[2] + a.fv[3]*a.fv[3]
                   + b.fv[0]*b.fv[0] + b.fv[1]*b.fv[1] + b.fv[2]*b.fv[2] + b.fv[3]*b.fv[3];
                union { bf16x8 v; unsigned u[4]; } fr;
                fr.u[0] = pack_bf16_trunc(a.u.x, a.u.y);
                fr.u[1] = pack_bf16_trunc(a.u.z, a.u.w);
                fr.u[2] = pack_bf16_trunc(b.u.x, b.u.y);
                fr.u[3] = pack_bf16_trunc(b.u.z, b.u.w);
                bfr[wm][kc] = fr.v;
            }
            c2a[wm] = c;
        }

        // ---- MFMA ----
        floatx4 acc[8][2];
        #pragma unroll
        for (int bt = 0; bt < 8; bt++) { acc[bt][0] = (floatx4)(0.f); acc[bt][1] = (floatx4)(0.f); }
        #pragma unroll
        for (int kc = 0; kc < 4; kc++) {
            #pragma unroll
            for (int bt = 0; bt < 8; bt++) {
                bf16x8 af = sm.n.A_lds[kc * 512 + bt * 64 + l];
                acc[bt][0] = __builtin_amdgcn_mfma_f32_16x16x32_bf16(af, bfr[0][kc], acc[bt][0], 0, 0, 0);
                acc[bt][1] = __builtin_amdgcn_mfma_f32_16x16x32_bf16(af, bfr[1][kc], acc[bt][1], 0, 0, 0);
            }
        }

        // ---- c2 reduce across lane quads ----
        float c2v[2];
        #pragma unroll
        for (int wm = 0; wm < 2; wm++) {
            float c = c2a[wm];
            c += __shfl_xor(c, 16, 64);
            c += __shfl_xor(c, 32, 64);
            c2v[wm] = c;
        }

        // ---- epilogue: underflow-vote fast path ----
        float dmin = 1e30f;
        #pragma unroll
        for (int bt = 0; bt < 8; bt++) {
            floatx4 f4 = *(const floatx4*)&sm.n.f2l[bt * 16 + q * 4];
            #pragma unroll
            for (int r = 0; r < 4; r++) {
                float d20 = fmaf(-2.f, acc[bt][0][r], f4[r] + c2v[0]);
                float d21 = fmaf(-2.f, acc[bt][1][r], f4[r] + c2v[1]);
                dmin = fminf(dmin, fminf(d20, d21));
            }
        }
        if (!__any(dmin < D2_CUT)) {
            sm.n.sred[w * 128 + l] = 0.f;
            sm.n.sred[w * 128 + l + 64] = 0.f;
        } else {
            float vm0 = (gm[0] < M_ && sm.n.msk[(w * 2 + 0) * 16 + n16] != 0) ? 1.f : 0.f;
            float vm1 = (gm[1] < M_ && sm.n.msk[(w * 2 + 1) * 16 + n16] != 0) ? 1.f : 0.f;
            #pragma unroll
            for (int bt = 0; bt < 8; bt++) {
                floatx4 f4 = *(const floatx4*)&sm.n.f2l[bt * 16 + q * 4];
                #pragma unroll
                for (int r = 0; r < 4; r++) {
                    float s = 0.f;
                    float d20 = fmaxf(fmaf(-2.f, acc[bt][0][r], f4[r] + c2v[0]), 0.f);
                    float d21 = fmaxf(fmaf(-2.f, acc[bt][1][r], f4[r] + c2v[1]), 0.f);
                    if (d20 < D2_CUT) s += vm0 * expf(-SCALE_ * sqrtf(d20));
                    if (d21 < D2_CUT) s += vm1 * expf(-SCALE_ * sqrtf(d21));
                    s = row16Sum(s);
                    if (n16 == 0) sm.n.sred[w * 128 + bt * 16 + q * 4 + r] = s;
                }
            }
        }
        __syncthreads();
        if (t < 128) {
            float s = sm.n.sred[t] + sm.n.sred[128 + t] + sm.n.sred[256 + t] + sm.n.sred[384 + t];
            atomicAdd(&s_neg[p * 128 + t], s);
        }
    }

    // ================= last-block finisher =================
    __threadfence();
    if (t == 0) last_flag = (atomicAdd(counter, 1) == TOTB_ - 1) ? 1 : 0;
    __syncthreads();
    if (!last_flag) return;
    __threadfence();   // acquire: all blocks' writes now visible

    // wave w handles p = w (128 entries over 64 lanes)
    {
        int base = w * 128 + l;
        float x0 = logf(s_pos[base]);
        float y0 = logf(s_neg[base]);
        float x1 = logf(s_pos[base + 64]);
        float y1 = logf(s_neg[base + 64]);
        float v = (-x0 + y0) + (-x1 + y1);
        v = waveSum64(v);
        if (l == 0) {
            float lv = v / (float)B_;
            if (isnan(lv)) lv = 0.f;
            lred[w] = lv;
        }
    }
    __syncthreads();
    if (t == 0) {
        float local_loss = (lred[0] + lred[1] + lred[2] + lred[3]) / (float)P_;
        double sxx = 0.0, syy = 0.0, sxy = 0.0;
        for (int i = 0; i < 128; i++) {
            sxx += mmd_part[i];
            syy += mmd_part[128 + i];
            sxy += mmd_part[256 + i];
        }
        double denom = 128.0 * 127.0;
        float mmd = (float)(sxx / denom + syy / denom - 2.0 * (sxy / (128.0 * 128.0)));
        out[0] = local_loss + mmd;
        out[1] = local_loss;
        out[2] = mmd;
    }
}

extern "C" void kernel_launch(void* const* d_in, const int* in_sizes, int n_in,
                              void* d_out, int out_size, void* d_ws, size_t ws_size,
                              hipStream_t stream) {
    const float* img     = (const float*)d_in[0];
    const float* txt     = (const float*)d_in[1];
    const float* local   = (const float*)d_in[2];
    const float* centers = (const float*)d_in[3];
    const int*   ci      = (const int*)d_in[4];
    const int*   posi    = (const int*)d_in[5];
    const int*   mvid    = (const int*)d_in[6];
    float* out = (float*)d_out;

    char* ws = (char*)d_ws;
    float*  s_neg    = (float*)(ws + 0);       // 2048 B
    int*    counter  = (int*)(ws + 2048);      // 4 B
    float*  s_pos    = (float*)(ws + 4096);    // 2048 B
    double* mmd_part = (double*)(ws + 8192);   // 3072 B

    hipMemsetAsync(ws, 0, 2052, stream);       // zero s_neg + counter
    k_main<<<TOTB_, 256, 0, stream>>>(local, centers, img, txt, ci, posi, mvid,
                                      s_neg, s_pos, mmd_part, counter, out);
}

// Round 6
// 330.056 us; speedup vs baseline: 2.6326x; 2.6326x over previous
//
#include <hip/hip_runtime.h>
#include <math.h>

#define B_ 128
#define D_ 128
#define P_ 4
#define M_ 100000
#define K_ 10
#define SCALE_ 10.0f
#define MB_ 782                 // ceil(100000/128)
#define NEG_BLOCKS (MB_ * P_)   // 3128
#define MMD_BLOCKS 128
#define POS_BLOCKS 128          // 512 (p,b) pairs / 4 waves
#define D2_CUT 120.0f           // d2 >= 120 -> exp(-10*sqrt(d2)) == 0.0f exactly (2^-158)

typedef short bf16x8 __attribute__((ext_vector_type(8)));
typedef float floatx4 __attribute__((ext_vector_type(4)));

// pack two fp32 -> two bf16 (truncate) in one v_perm_b32
__device__ inline unsigned pack_bf16_trunc(unsigned f0, unsigned f1) {
    return __builtin_amdgcn_perm(f1, f0, 0x07060302u);
}

// ---------- cross-lane helpers ----------
template <int CTRL>
__device__ inline float dpp_add(float v) {
    int x = __builtin_amdgcn_update_dpp(0, __builtin_bit_cast(int, v), CTRL, 0xF, 0xF, true);
    return v + __builtin_bit_cast(float, x);
}
__device__ inline float row16Sum(float v) {          // sum over lanes sharing l>>4
    v = dpp_add<0xB1>(v);
    v = dpp_add<0x4E>(v);
    v = dpp_add<0x141>(v);
    v = dpp_add<0x140>(v);
    return v;
}
__device__ inline float waveSum64(float v) {
    v = row16Sum(v);
    v += __shfl_xor(v, 16, 64);
    v += __shfl_xor(v, 32, 64);
    return v;
}
// legacy shfl butterfly (kept for mmd path: preserves round-3 summation order)
__device__ inline float waveReduceSumOld(float v) {
    #pragma unroll
    for (int off = 32; off > 0; off >>= 1) v += __shfl_xor(v, off, 64);
    return v;
}
__device__ inline float blockReduce128(float v, float* sh2) {  // 128-thread blocks
    v = waveSum64(v);
    int wid = threadIdx.x >> 6;
    if ((threadIdx.x & 63) == 0) sh2[wid] = v;
    __syncthreads();
    float r = sh2[0] + sh2[1];
    __syncthreads();
    return r;
}

// ---------- kernel A: normalize (transposed out) + f2 + zero s_neg ----------
__global__ __launch_bounds__(128) void k_prep(const float* __restrict__ img,
                                              const float* __restrict__ txt,
                                              const float* __restrict__ local,
                                              float* imgT, float* txtT,
                                              float* a2i, float* a2t,
                                              float* f2w, float* s_neg) {
    __shared__ float sh2[2];
    int bid = blockIdx.x, t = threadIdx.x;
    if (bid < 256) {
        int row = bid & 127, which = bid >> 7;
        if (bid < 4) s_neg[bid * 128 + t] = 0.f;
        const float* src = which ? txt : img;
        float* dstT = which ? txtT : imgT;
        float* a2 = which ? a2t : a2i;
        float v = src[row * D_ + t];
        float s = blockReduce128(v * v, sh2);
        float n = v / sqrtf(s);
        dstT[t * 128 + row] = n;                  // transposed for coalesced mmd stream
        float s2 = blockReduce128(n * n, sh2);
        if (t == 0) a2[row] = s2;
    } else {
        int r = bid - 256;                        // 0..511 = (p,b)
        float v = local[(size_t)r * D_ + t];
        float s = blockReduce128(v * v, sh2);
        if (t == 0) f2w[r] = s;
    }
}

// ---------- kernel B: fused neg (MFMA) + mmd + pos ----------
// (256,3): r3-proven spill-free register budget; r4's (256,4) spilled 46MB.
__global__ __launch_bounds__(256, 3) void k_main(const float* __restrict__ local,
                                                 const float* __restrict__ centers,
                                                 const float* __restrict__ imgT,
                                                 const float* __restrict__ txtT,
                                                 const float* __restrict__ a2i,
                                                 const float* __restrict__ a2t,
                                                 const int* __restrict__ ci,
                                                 const int* __restrict__ posi,
                                                 const int* __restrict__ mvid,
                                                 const float* __restrict__ f2w,
                                                 float* __restrict__ s_neg,
                                                 float* __restrict__ s_pos,
                                                 double* __restrict__ mmd_part,
                                                 float* __restrict__ out) {
    union Smem {
        struct {
            bf16x8 A_lds[2048];     // 32 KB, fragment order
            float sred[512];
            float f2l[128];
            unsigned char msk[128];
        } n;
        struct {
            float ri[128], rt[128];
            float sh2[2];
        } m;
    };
    __shared__ Smem sm;
    const int bid = blockIdx.x;
    const int t = threadIdx.x;
    const int w = t >> 6;
    const int l = t & 63;

    if (bid < NEG_BLOCKS) {
        // ================= neg =================
        const int p = bid / MB_;
        const int mb = bid - p * MB_;
        const int m0 = mb * 128;
        const int n16 = l & 15;
        const int q = l >> 4;

        // ---- stage A = local[p] as bf16 fragments; msk init; f2 to LDS ----
        const float* lp = local + (size_t)p * B_ * D_;
        if (t < 128) { sm.n.msk[t] = 1; sm.n.f2l[t] = f2w[p * 128 + t]; }
        #pragma unroll
        for (int s8 = 0; s8 < 8; s8++) {
            int f = t + 256 * s8;
            int fl = f & 63, bt = (f >> 6) & 7, kc = f >> 9;
            int row = bt * 16 + (fl & 15);
            int col = kc * 32 + ((fl >> 4) & 3) * 8;
            const uint4 u0 = *(const uint4*)(lp + row * D_ + col);
            const uint4 u1 = *(const uint4*)(lp + row * D_ + col + 4);
            union { bf16x8 v; unsigned u[4]; } fr;
            fr.u[0] = pack_bf16_trunc(u0.x, u0.y);
            fr.u[1] = pack_bf16_trunc(u0.z, u0.w);
            fr.u[2] = pack_bf16_trunc(u1.x, u1.y);
            fr.u[3] = pack_bf16_trunc(u1.z, u1.w);
            sm.n.A_lds[f] = fr.v;
        }
        __syncthreads();

        // ---- issue ALL B loads (16 x 16B in flight per thread) ----
        int gm[2];
        gm[0] = m0 + (w * 2 + 0) * 16 + n16;
        gm[1] = m0 + (w * 2 + 1) * 16 + n16;
        const float* cb = centers + (size_t)p * M_ * D_;
        uint4 rb[2][4][2];
        if (m0 + 128 <= M_) {
            #pragma unroll
            for (int wm = 0; wm < 2; wm++) {
                const uint4* src = (const uint4*)(cb + (size_t)gm[wm] * D_ + q * 8);
                #pragma unroll
                for (int kc = 0; kc < 4; kc++) {
                    rb[wm][kc][0] = src[kc * 8];
                    rb[wm][kc][1] = src[kc * 8 + 1];
                }
            }
        } else {
            const uint4 z = make_uint4(0u, 0u, 0u, 0u);
            #pragma unroll
            for (int wm = 0; wm < 2; wm++) {
                const uint4* src = (const uint4*)(cb + (size_t)gm[wm] * D_ + q * 8);
                #pragma unroll
                for (int kc = 0; kc < 4; kc++) {
                    if (gm[wm] < M_) {
                        rb[wm][kc][0] = src[kc * 8];
                        rb[wm][kc][1] = src[kc * 8 + 1];
                    } else {
                        rb[wm][kc][0] = z;
                        rb[wm][kc][1] = z;
                    }
                }
            }
        }

        // ---- scatter mask zeros (overlaps load latency) ----
        #pragma unroll
        for (int i = 0; i < 5; i++) {             // 5*256 = B_*K_
            int idx = ci[t + 256 * i];
            unsigned r = (unsigned)(idx - m0);
            if (r < 128u) sm.n.msk[r] = 0;
        }
        if (t < B_) {
            unsigned r = (unsigned)(posi[t] - m0);
            if (r < 128u) sm.n.msk[r] = 0;
        }
        __syncthreads();   // msk scatter visible before epilogue reads

        // ---- c2 + convert to bf16 fragments ----
        float c2a[2];
        bf16x8 bfr[2][4];
        #pragma unroll
        for (int wm = 0; wm < 2; wm++) {
            float c = 0.f;
            #pragma unroll
            for (int kc = 0; kc < 4; kc++) {
                union { uint4 u; floatx4 f; } a, b;
                a.u = rb[wm][kc][0];
                b.u = rb[wm][kc][1];
                c += a.f[0]*a.f[0] + a.f[1]*a.f[1] + a.f[2]*a.f[2] + a.f[3]*a.f[3]
                   + b.f[0]*b.f[0] + b.f[1]*b.f[1] + b.f[2]*b.f[2] + b.f[3]*b.f[3];
                union { bf16x8 v; unsigned u[4]; } fr;
                fr.u[0] = pack_bf16_trunc(a.u.x, a.u.y);
                fr.u[1] = pack_bf16_trunc(a.u.z, a.u.w);
                fr.u[2] = pack_bf16_trunc(b.u.x, b.u.y);
                fr.u[3] = pack_bf16_trunc(b.u.z, b.u.w);
                bfr[wm][kc] = fr.v;
            }
            c2a[wm] = c;
        }

        // ---- MFMA ----
        floatx4 acc[8][2];
        #pragma unroll
        for (int bt = 0; bt < 8; bt++) { acc[bt][0] = (floatx4)(0.f); acc[bt][1] = (floatx4)(0.f); }
        #pragma unroll
        for (int kc = 0; kc < 4; kc++) {
            #pragma unroll
            for (int bt = 0; bt < 8; bt++) {
                bf16x8 af = sm.n.A_lds[kc * 512 + bt * 64 + l];
                acc[bt][0] = __builtin_amdgcn_mfma_f32_16x16x32_bf16(af, bfr[0][kc], acc[bt][0], 0, 0, 0);
                acc[bt][1] = __builtin_amdgcn_mfma_f32_16x16x32_bf16(af, bfr[1][kc], acc[bt][1], 0, 0, 0);
            }
        }

        // ---- c2 reduce across lane quads ----
        float c2v[2];
        #pragma unroll
        for (int wm = 0; wm < 2; wm++) {
            float c = c2a[wm];
            c += __shfl_xor(c, 16, 64);
            c += __shfl_xor(c, 32, 64);
            c2v[wm] = c;
        }

        // ---- epilogue: underflow-vote fast path ----
        float dmin = 1e30f;
        #pragma unroll
        for (int bt = 0; bt < 8; bt++) {
            floatx4 f4 = *(const floatx4*)&sm.n.f2l[bt * 16 + q * 4];
            #pragma unroll
            for (int r = 0; r < 4; r++) {
                float d20 = fmaf(-2.f, acc[bt][0][r], f4[r] + c2v[0]);
                float d21 = fmaf(-2.f, acc[bt][1][r], f4[r] + c2v[1]);
                dmin = fminf(dmin, fminf(d20, d21));
            }
        }
        if (!__any(dmin < D2_CUT)) {
            // all 64 contributions underflow to exactly 0.0f (d2>=120 -> e<2^-158)
            sm.n.sred[w * 128 + l] = 0.f;
            sm.n.sred[w * 128 + l + 64] = 0.f;
        } else {
            // faithful slow path (cold)
            float vm0 = (gm[0] < M_ && sm.n.msk[(w * 2 + 0) * 16 + n16] != 0) ? 1.f : 0.f;
            float vm1 = (gm[1] < M_ && sm.n.msk[(w * 2 + 1) * 16 + n16] != 0) ? 1.f : 0.f;
            #pragma unroll
            for (int bt = 0; bt < 8; bt++) {
                floatx4 f4 = *(const floatx4*)&sm.n.f2l[bt * 16 + q * 4];
                #pragma unroll
                for (int r = 0; r < 4; r++) {
                    float s = 0.f;
                    float d20 = fmaxf(fmaf(-2.f, acc[bt][0][r], f4[r] + c2v[0]), 0.f);
                    float d21 = fmaxf(fmaf(-2.f, acc[bt][1][r], f4[r] + c2v[1]), 0.f);
                    if (d20 < D2_CUT) s += vm0 * expf(-SCALE_ * sqrtf(d20));
                    if (d21 < D2_CUT) s += vm1 * expf(-SCALE_ * sqrtf(d21));
                    s = row16Sum(s);
                    if (n16 == 0) sm.n.sred[w * 128 + bt * 16 + q * 4 + r] = s;
                }
            }
        }
        __syncthreads();
        if (t < 128) {
            float s = sm.n.sred[t] + sm.n.sred[128 + t] + sm.n.sred[256 + t] + sm.n.sred[384 + t];
            atomicAdd(&s_neg[p * 128 + t], s);
        }
    } else if (bid < NEG_BLOCKS + MMD_BLOCKS) {
        // ================= mmd (row i); threads 0-127 active, coalesced stream =================
        const int i = bid - NEG_BLOCKS;
        if (t < 128) {
            sm.m.ri[t] = imgT[t * 128 + i];      // row i gather (once)
            sm.m.rt[t] = txtT[t * 128 + i];
        }
        __syncthreads();
        float kxx = 0.f, kyy = 0.f, kxy = 0.f;
        if (t < 128) {
            float dxx = 0.f, dyy = 0.f, dxy = 0.f;
            #pragma unroll 4
            for (int d = 0; d < D_; d++) {
                float rid = sm.m.ri[d], rtd = sm.m.rt[d];
                float av = imgT[d * 128 + t];    // coalesced
                float bv = txtT[d * 128 + t];
                dxx = fmaf(rid, av, dxx);
                dyy = fmaf(rtd, bv, dyy);
                dxy = fmaf(rid, bv, dxy);
            }
            kxx = (i == t) ? 0.f : expf(-fmaxf(a2i[i] + a2i[t] - 2.f * dxx, 0.f) * 0.5f);
            kyy = (i == t) ? 0.f : expf(-fmaxf(a2t[i] + a2t[t] - 2.f * dyy, 0.f) * 0.5f);
            kxy = expf(-fmaxf(a2i[i] + a2t[t] - 2.f * dxy, 0.f) * 0.5f);
        }
        float sxx = waveReduceSumOld(kxx);
        float syy = waveReduceSumOld(kyy);
        float sxy = waveReduceSumOld(kxy);
        __syncthreads();
        if (t == 0)  { sm.m.sh2[0] = sxx; }
        if (t == 64) { sm.m.sh2[1] = sxx; }
        __syncthreads();
        float txx = sm.m.sh2[0] + sm.m.sh2[1];
        __syncthreads();
        if (t == 0)  { sm.m.sh2[0] = syy; }
        if (t == 64) { sm.m.sh2[1] = syy; }
        __syncthreads();
        float tyy = sm.m.sh2[0] + sm.m.sh2[1];
        __syncthreads();
        if (t == 0)  { sm.m.sh2[0] = sxy; }
        if (t == 64) { sm.m.sh2[1] = sxy; }
        __syncthreads();
        float txy = sm.m.sh2[0] + sm.m.sh2[1];
        if (t == 0) {
            mmd_part[i] = (double)txx;
            mmd_part[128 + i] = (double)tyy;
            mmd_part[256 + i] = (double)txy;
        }
    } else {
        // ================= pos: one wave per (p,b), 4 per block =================
        const int pair = (bid - (NEG_BLOCKS + MMD_BLOCKS)) * 4 + w;  // 0..511
        const int p = pair >> 7, b = pair & 127;
        const float* f = local + (size_t)pair * D_;
        float f0 = f[l], f1 = f[l + 64];
        float f2v = f2w[pair];
        const float* cb = centers + (size_t)p * M_ * D_;
        float s = 0.f;
        #pragma unroll
        for (int k = 0; k < K_; k++) {
            int idx = ci[b * K_ + k];
            const float* c = cb + (size_t)idx * D_;
            float c0 = c[l], c1 = c[l + 64];
            float p2 = waveSum64(c0 * c0 + c1 * c1);
            float fp = waveSum64(f0 * c0 + f1 * c1);
            float d2 = fmaxf(f2v + p2 - 2.f * fp, 0.f);
            if (d2 < D2_CUT) s += expf(-SCALE_ * sqrtf(d2));   // wave-uniform branch
        }
        if (l == 0) s_pos[pair] = s;
        if (p == 0 && l < K_) {
            int ix = ci[b * K_ + l];
            out[3 + b * K_ + l] = (float)mvid[ix];
        }
    }
}

// ---------- kernel C: final scalars ----------
__global__ __launch_bounds__(512) void k_final(const float* __restrict__ s_pos,
                                               const float* __restrict__ s_neg,
                                               const double* __restrict__ mmd_part,
                                               float* out) {
    __shared__ float red[512];
    __shared__ float lp_[4];
    int t = threadIdx.x;
    float x = logf(s_pos[t]);
    float y = logf(s_neg[t]);
    red[t] = -x + y;
    __syncthreads();
    for (int s = 64; s > 0; s >>= 1) {
        if ((t & 127) < s) red[t] += red[t + s];
        __syncthreads();
    }
    if ((t & 127) == 0) {
        float lv = red[t] / (float)B_;
        if (isnan(lv)) lv = 0.f;
        lp_[t >> 7] = lv;
    }
    __syncthreads();
    if (t == 0) {
        float local_loss = (lp_[0] + lp_[1] + lp_[2] + lp_[3]) / (float)P_;
        double sxx = 0.0, syy = 0.0, sxy = 0.0;
        for (int i = 0; i < 128; i++) {
            sxx += mmd_part[i];
            syy += mmd_part[128 + i];
            sxy += mmd_part[256 + i];
        }
        double denom = 128.0 * 127.0;
        float mmd = (float)(sxx / denom + syy / denom - 2.0 * (sxy / (128.0 * 128.0)));
        out[0] = local_loss + mmd;
        out[1] = local_loss;
        out[2] = mmd;
    }
}

extern "C" void kernel_launch(void* const* d_in, const int* in_sizes, int n_in,
                              void* d_out, int out_size, void* d_ws, size_t ws_size,
                              hipStream_t stream) {
    const float* img     = (const float*)d_in[0];
    const float* txt     = (const float*)d_in[1];
    const float* local   = (const float*)d_in[2];
    const float* centers = (const float*)d_in[3];
    const int*   ci      = (const int*)d_in[4];
    const int*   posi    = (const int*)d_in[5];
    const int*   mvid    = (const int*)d_in[6];
    float* out = (float*)d_out;

    char* ws = (char*)d_ws;
    float*  imgT     = (float*)(ws + 0);
    float*  txtT     = (float*)(ws + 65536);
    float*  a2i      = (float*)(ws + 131072);
    float*  a2t      = (float*)(ws + 131584);
    float*  f2w      = (float*)(ws + 132096);
    float*  s_pos    = (float*)(ws + 134144);
    float*  s_neg    = (float*)(ws + 136192);
    double* mmd_part = (double*)(ws + 138240);

    k_prep<<<768, 128, 0, stream>>>(img, txt, local, imgT, txtT, a2i, a2t, f2w, s_neg);
    k_main<<<NEG_BLOCKS + MMD_BLOCKS + POS_BLOCKS, 256, 0, stream>>>(
        local, centers, imgT, txtT, a2i, a2t, ci, posi, mvid, f2w,
        s_neg, s_pos, mmd_part, out);
    k_final<<<1, 512, 0, stream>>>(s_pos, s_neg, mmd_part, out);
}